// Round 1
// baseline (1352.597 us; speedup 1.0000x reference)
//
#include <hip/hip_runtime.h>
#include <stdint.h>

// FlashbackPlusPlus: embed->GRU->spatiotemporal causal attention->FC
// S=256 U=64 H=256 V=10000
#define S_LEN 256
#define U_LEN 64
#define H_DIM 256
#define V_DIM 10000
#define Y_ELEMS 163840000LL  // S*U*V

typedef short bf16x8 __attribute__((ext_vector_type(8)));
typedef float f32x4 __attribute__((ext_vector_type(4)));

__device__ __forceinline__ short f2bf(float f) {
  union { float f; uint32_t u; } v; v.f = f;
  uint32_t r = v.u + 0x7FFFu + ((v.u >> 16) & 1u);  // RNE
  return (short)(r >> 16);
}
__device__ __forceinline__ float bf2f(short s) {
  union { uint32_t u; float f; } v; v.u = ((uint32_t)(uint16_t)s) << 16;
  return v.f;
}

// global -> LDS async copy, 16B per lane. LDS dest = wave-uniform base + lane*16.
__device__ __forceinline__ void gload_lds16(const void* g, void* l) {
  __builtin_amdgcn_global_load_lds(
      (const __attribute__((address_space(1))) char*)(uintptr_t)g,
      (__attribute__((address_space(3))) char*)(uintptr_t)l, 16, 0, 0);
}

// ---------------------------------------------------------------------------
// prep: f32->bf16 weight conversions + A2 user-embedding half
// ---------------------------------------------------------------------------
__global__ __launch_bounds__(256) void fpp_prep(
    const float* __restrict__ enc_W, const float* __restrict__ W_ih,
    const float* __restrict__ fc_W, const float* __restrict__ user_W,
    const int* __restrict__ active_user,
    short* __restrict__ encWb, short* __restrict__ WihB,
    short* __restrict__ fcWb, short* __restrict__ A2) {
  const int tid = blockIdx.x * 256 + threadIdx.x;
  const int stride = gridDim.x * 256;
  for (int i = tid; i < V_DIM * H_DIM; i += stride) encWb[i] = f2bf(enc_W[i]);
  for (int i = tid; i < 3 * H_DIM * H_DIM; i += stride) WihB[i] = f2bf(W_ih[i]);
  for (int i = tid; i < V_DIM * 2 * H_DIM; i += stride) fcWb[i] = f2bf(fc_W[i]);
  // A2 rows r = s*64+u ; cols [256,512) = user_W[active_user[u]]
  for (int i = tid; i < 16384 * 256; i += stride) {
    const int row = i >> 8, k = i & 255;
    const int au = active_user[row & 63];
    A2[(int64_t)row * 512 + 256 + k] = f2bf(user_W[(int64_t)au * 256 + k]);
  }
}

// ---------------------------------------------------------------------------
// GEMM (B^T form): C[m,n] = sum_k A[m,k]*B[n,k] (+bias1[n] (+bias2[n] if n<lim))
// bf16 inputs, f32 accum; 128x128 tile, BK=64, 4 waves, double-buffered LDS,
// global_load_lds staging (m97 structure).
// ---------------------------------------------------------------------------
template <bool OUT_BF16>
__global__ __launch_bounds__(256) void fpp_gemm_bt(
    const short* __restrict__ A, const short* __restrict__ B, void* __restrict__ C,
    const float* __restrict__ bias1, const float* __restrict__ bias2, int bias2_limit,
    int M, int N, int K, int ldc, int MT, int NT, int SUPER) {
  // m-supertile mapping: SUPER consecutive m-tiles share the whole B panel in L2
  const int bid = blockIdx.x;
  const int per_super = SUPER * NT;
  const int srow = bid / per_super;
  const int rrem = bid - srow * per_super;
  const int mi = srow * SUPER + (rrem % SUPER);
  const int ni = rrem / SUPER;
  const int m0 = mi * 128, n0 = ni * 128;

  __shared__ __attribute__((aligned(16))) short As[2][128 * 64];
  __shared__ __attribute__((aligned(16))) short Bs[2][128 * 64];

  const int tid = threadIdx.x;
  const int lane = tid & 63;
  const int wv = tid >> 6;
  const int wr = wv >> 1, wc = wv & 1;

  f32x4 acc[4][4];
#pragma unroll
  for (int a_ = 0; a_ < 4; ++a_)
#pragma unroll
    for (int b_ = 0; b_ < 4; ++b_) acc[a_][b_] = f32x4{0.f, 0.f, 0.f, 0.f};

  auto stage = [&](int buf, int k0) {
#pragma unroll
    for (int c = 0; c < 4; ++c) {
      const int chunk = c * 256 + tid;        // 16B chunk id
      const int row = chunk >> 3, kc8 = chunk & 7;
      int gr = m0 + row; gr = (gr < M) ? gr : (M - 1);
      gload_lds16(A + (int64_t)gr * K + k0 + kc8 * 8,
                  (char*)&As[buf][0] + (c * 256 + wv * 64) * 16);
    }
#pragma unroll
    for (int c = 0; c < 4; ++c) {
      const int chunk = c * 256 + tid;
      const int row = chunk >> 3, kc8 = chunk & 7;
      int gn = n0 + row; gn = (gn < N) ? gn : (N - 1);
      gload_lds16(B + (int64_t)gn * K + k0 + kc8 * 8,
                  (char*)&Bs[buf][0] + (c * 256 + wv * 64) * 16);
    }
  };

  const int nk = K >> 6;
  stage(0, 0);
  asm volatile("s_waitcnt vmcnt(0)" ::: "memory");
  __syncthreads();
  for (int ks = 0; ks < nk; ++ks) {
    const int cur = ks & 1;
    if (ks + 1 < nk) stage(cur ^ 1, (ks + 1) << 6);  // async prefetch next K-tile
#pragma unroll
    for (int kk = 0; kk < 2; ++kk) {
      bf16x8 af[4], bfr[4];
#pragma unroll
      for (int mt = 0; mt < 4; ++mt)
        af[mt] = *(const bf16x8*)&As[cur][(wr * 64 + mt * 16 + (lane & 15)) * 64 +
                                          kk * 32 + (lane >> 4) * 8];
#pragma unroll
      for (int nt = 0; nt < 4; ++nt)
        bfr[nt] = *(const bf16x8*)&Bs[cur][(wc * 64 + nt * 16 + (lane & 15)) * 64 +
                                           kk * 32 + (lane >> 4) * 8];
#pragma unroll
      for (int mt = 0; mt < 4; ++mt)
#pragma unroll
        for (int nt = 0; nt < 4; ++nt)
          acc[mt][nt] = __builtin_amdgcn_mfma_f32_16x16x32_bf16(
              af[mt], bfr[nt], acc[mt][nt], 0, 0, 0);
    }
    asm volatile("s_waitcnt vmcnt(0)" ::: "memory");
    __syncthreads();
  }

  // epilogue: D layout row=(lane>>4)*4+r (M dim), col=lane&15 (N dim)
#pragma unroll
  for (int nt = 0; nt < 4; ++nt) {
    const int col = n0 + wc * 64 + nt * 16 + (lane & 15);
    if (col >= N) continue;
    float badd = 0.f;
    if (bias1) badd += bias1[col];
    if (bias2 && col < bias2_limit) badd += bias2[col];
#pragma unroll
    for (int mt = 0; mt < 4; ++mt) {
      const int rbase = m0 + wr * 64 + mt * 16 + (lane >> 4) * 4;
#pragma unroll
      for (int r = 0; r < 4; ++r) {
        const int row = rbase + r;
        if (row < M) {
          const float v = acc[mt][nt][r] + badd;
          if (OUT_BF16)
            ((short*)C)[(int64_t)row * ldc + col] = f2bf(v);
          else
            ((float*)C)[(int64_t)row * ldc + col] = v;
        }
      }
    }
  }
}

// ---------------------------------------------------------------------------
// GRU: 4 blocks x 16 users x 8 waves. W_hh bf16 fragments resident in VGPRs
// (48 frags = 192 VGPR/wave). Wave w owns gate-triples for c in [32w,32w+32):
// tiles {r0,r1,z0,z1,n0,n1} -> gates are acc-register-local. gi rows staged
// async to LDS via global_load_lds with XOR swizzle. 2 barriers/step.
// ---------------------------------------------------------------------------
__global__ __launch_bounds__(512) void fpp_gru(
    const int* __restrict__ x, const float* __restrict__ h0,
    const float* __restrict__ W_hh, const float* __restrict__ b_hh,
    const short* __restrict__ giV, float* __restrict__ out,
    float* __restrict__ hlast) {
  __shared__ __attribute__((aligned(16))) short h_lds[16 * 264];   // [u][c] pad 8
  __shared__ __attribute__((aligned(16))) short gi_lds[16 * 768];  // [u][n] swizzled
  __shared__ __attribute__((aligned(16))) int x_lds[256 * 16];

  const int tid = threadIdx.x;
  const int lane = tid & 63;
  const int wv = tid >> 6;  // wave 0..7
  const int u0 = blockIdx.x * 16;
  const int g = lane >> 4;
  const int lo = lane & 15;

  for (int i = tid; i < 256 * 16; i += 512)
    x_lds[i] = x[(i >> 4) * 64 + u0 + (i & 15)];

  // preload W_hh B-fragments: B_op[k][n] = W_hh[n][k]; lane: n=n0t+lo, k=kc*32+g*8+j
  bf16x8 Wf[6][8];
  {
    const int n0t[6] = {32 * wv,       32 * wv + 16,       256 + 32 * wv,
                        256 + 32 * wv + 16, 512 + 32 * wv, 512 + 32 * wv + 16};
#pragma unroll
    for (int tt = 0; tt < 6; ++tt) {
      const float* wrow = W_hh + (int64_t)(n0t[tt] + lo) * 256 + g * 8;
#pragma unroll
      for (int kc = 0; kc < 8; ++kc) {
        const float* p = wrow + kc * 32;
        bf16x8 f;
#pragma unroll
        for (int j = 0; j < 8; ++j) f[j] = f2bf(p[j]);
        Wf[tt][kc] = f;
      }
    }
  }
  // b_hh for n-gate (r/z parts folded into giV); b_hh[n], n = 512 + 32w + 16tp + lo
  const float bhh0 = b_hh[512 + 32 * wv + lo];
  const float bhh1 = b_hh[512 + 32 * wv + 16 + lo];

  // h cells owned by this lane: u = g*4+r, c = 32w + tp*16 + lo
  float hreg[2][4];
#pragma unroll
  for (int tp = 0; tp < 2; ++tp)
#pragma unroll
    for (int r = 0; r < 4; ++r) {
      const int u = g * 4 + r, c = 32 * wv + tp * 16 + lo;
      const float v = h0[(u0 + u) * 256 + c];
      hreg[tp][r] = v;
      h_lds[u * 264 + c] = f2bf(v);
    }
  __syncthreads();

  for (int s = 0; s < 256; ++s) {
    // async-stage gi rows for users 2w, 2w+1 (3 calls x 1KB), XOR-swizzled
    {
      const int xid0 = x_lds[s * 16 + 2 * wv];
      const int xid1 = x_lds[s * 16 + 2 * wv + 1];
#pragma unroll
      for (int c = 0; c < 3; ++c) {
        const int p = c * 64 + lane;          // 0..191 over the 2-row region
        const int prow = (p >= 96) ? 1 : 0;
        const int pin = p - prow * 96;        // chunk within row
        const int uu = 2 * wv + prow;
        const int xid = prow ? xid1 : xid0;
        const int o = pin ^ (((uu >> 2) & 3) << 1);  // inverse swizzle on source
        gload_lds16(giV + (int64_t)xid * 768 + o * 8,
                    (char*)gi_lds + (2 * wv * 96 + c * 64) * 16);
      }
    }

    // gh = h @ W_hh^T : 48 MFMAs, acc[4],acc[5] init with b_hh (n-gate)
    f32x4 acc[6];
#pragma unroll
    for (int tt = 0; tt < 4; ++tt) acc[tt] = f32x4{0.f, 0.f, 0.f, 0.f};
    acc[4] = f32x4{bhh0, bhh0, bhh0, bhh0};
    acc[5] = f32x4{bhh1, bhh1, bhh1, bhh1};
#pragma unroll
    for (int kc = 0; kc < 8; ++kc) {
      const bf16x8 a = *(const bf16x8*)&h_lds[lo * 264 + kc * 32 + g * 8];
#pragma unroll
      for (int tt = 0; tt < 6; ++tt)
        acc[tt] = __builtin_amdgcn_mfma_f32_16x16x32_bf16(a, Wf[tt][kc], acc[tt], 0, 0, 0);
    }
    asm volatile("s_waitcnt vmcnt(0)" ::: "memory");  // gi landed (covered by MFMA phase)
    __syncthreads();                                  // barrier1: gi visible, h reads done

    // gates: fully register-local (acc tiles align with cell ownership)
#pragma unroll
    for (int tp = 0; tp < 2; ++tp) {
#pragma unroll
      for (int r = 0; r < 4; ++r) {
        const int u = g * 4 + r;
        const int c = 32 * wv + tp * 16 + lo;
        const int sw = ((u >> 2) & 3) << 5;
        const float gir = bf2f(*(const short*)((const char*)gi_lds + u * 1536 + ((2 * c) ^ sw)));
        const float giz = bf2f(*(const short*)((const char*)gi_lds + u * 1536 + ((2 * (256 + c)) ^ sw)));
        const float gin = bf2f(*(const short*)((const char*)gi_lds + u * 1536 + ((2 * (512 + c)) ^ sw)));
        const float xr = acc[0 + tp][r] + gir;
        const float rr = __builtin_amdgcn_rcpf(1.f + __builtin_amdgcn_exp2f(-1.4426950408889634f * xr));
        const float xz = acc[2 + tp][r] + giz;
        const float zz = __builtin_amdgcn_rcpf(1.f + __builtin_amdgcn_exp2f(-1.4426950408889634f * xz));
        float xn = gin + rr * acc[4 + tp][r];
        xn = fminf(fmaxf(xn, -12.f), 12.f);
        const float E = __builtin_amdgcn_exp2f(2.8853900817779268f * xn);
        const float nn = (E - 1.f) * __builtin_amdgcn_rcpf(E + 1.f);
        const float hv = nn + zz * (hreg[tp][r] - nn);
        hreg[tp][r] = hv;
        h_lds[u * 264 + c] = f2bf(hv);
        out[((int64_t)s * 64 + u0 + u) * 256 + c] = hv;
      }
    }
    __syncthreads();  // barrier2: h writes visible before next MFMA phase
  }

#pragma unroll
  for (int tp = 0; tp < 2; ++tp)
#pragma unroll
    for (int r = 0; r < 4; ++r) {
      const int u = g * 4 + r, c = 32 * wv + tp * 16 + lo;
      hlast[(u0 + u) * 256 + c] = hreg[tp][r];
    }
}

// ---------------------------------------------------------------------------
// attention: per (u, i-block of 64): loop causal j-blocks; w in LDS; weighted
// sum of GRU hiddens; writes bf16 into A2[:, 0:256]. f32 vector math.
// ---------------------------------------------------------------------------
__global__ __launch_bounds__(256) void fpp_attn(
    const float* __restrict__ t_g, const float* __restrict__ s_g,
    const float* __restrict__ gout, short* __restrict__ A2) {
  const int u = blockIdx.x;   // 0..63
  const int ib = blockIdx.y;  // 0..3
  const int tid = threadIdx.x;
  const int iloc = tid >> 2;  // 0..63
  const int q = tid & 3;      // h quarter (64 each)

  __shared__ __attribute__((aligned(16))) float out_lds[64][272];  // q-seg stride 68
  __shared__ __attribute__((aligned(16))) float w_lds[64][65];
  __shared__ float ti[64], si0[64], si1[64], tj[64], sj0[64], sj1[64], sum_lds[64];

  if (tid < 64) {
    const int ig = ib * 64 + tid;
    ti[tid] = t_g[ig * 64 + u];
    si0[tid] = s_g[(ig * 64 + u) * 2 + 0];
    si1[tid] = s_g[(ig * 64 + u) * 2 + 1];
    sum_lds[tid] = 0.f;
  }

  f32x4 accv[16];
#pragma unroll
  for (int hh = 0; hh < 16; ++hh) accv[hh] = f32x4{0.f, 0.f, 0.f, 0.f};

  const int igl = ib * 64 + iloc;

  for (int jb = 0; jb <= ib; ++jb) {
    __syncthreads();  // protect LDS vs previous iteration readers
    {
      const int jj = tid >> 2;
      const float* src = gout + ((int64_t)(jb * 64 + jj) * 64 + u) * 256 + q * 64;
#pragma unroll
      for (int hh = 0; hh < 16; ++hh)
        *(f32x4*)&out_lds[jj][q * 68 + hh * 4] = *(const f32x4*)(src + hh * 4);
    }
    if (tid < 64) {
      const int jg = jb * 64 + tid;
      tj[tid] = t_g[jg * 64 + u];
      sj0[tid] = s_g[(jg * 64 + u) * 2 + 0];
      sj1[tid] = s_g[(jg * 64 + u) * 2 + 1];
    }
    __syncthreads();
    {
      const float tiv = ti[iloc], p0 = si0[iloc], p1 = si1[iloc];
#pragma unroll
      for (int jj = 0; jj < 16; ++jj) {
        const int j = q * 16 + jj;
        const int jgl = jb * 64 + j;
        const float dt = tiv - tj[j];
        // f_t = (cos(2*pi*dt)+1)*0.5*exp(-0.1*dt); v_cos takes revolutions
        const float ft = (__builtin_amdgcn_cosf(dt) + 1.f) * 0.5f *
                         __builtin_amdgcn_exp2f(-0.14426950408889634f * dt);
        const float dx = p0 - sj0[j], dy = p1 - sj1[j];
        const float ds = __builtin_amdgcn_sqrtf(dx * dx + dy * dy);
        const float fs = __builtin_amdgcn_exp2f(-144.26950408889634f * ds);
        float wvv = ft * fs + 1e-10f;
        if (jgl > igl) wvv = 0.f;  // causal
        w_lds[iloc][j] = wvv;
      }
    }
    __syncthreads();
    if (tid < 64) {
      float sm = 0.f;
#pragma unroll
      for (int j = 0; j < 64; ++j) sm += w_lds[tid][j];
      sum_lds[tid] += sm;
    }
    for (int j = 0; j < 64; ++j) {
      const float wvv = w_lds[iloc][j];
#pragma unroll
      for (int hh = 0; hh < 16; ++hh) {
        const f32x4 o = *(const f32x4*)&out_lds[j][q * 68 + hh * 4];
        accv[hh] += o * wvv;
      }
    }
  }
  __syncthreads();
  const float inv = 1.f / sum_lds[iloc];
  short* dst = A2 + (int64_t)((ib * 64 + iloc) * 64 + u) * 512 + q * 64;
#pragma unroll
  for (int hh = 0; hh < 16; ++hh) {
    const f32x4 v = accv[hh] * inv;
    short4 sv;
    sv.x = f2bf(v[0]); sv.y = f2bf(v[1]); sv.z = f2bf(v[2]); sv.w = f2bf(v[3]);
    *(short4*)(dst + hh * 4) = sv;
  }
}

// ---------------------------------------------------------------------------
extern "C" void kernel_launch(void* const* d_in, const int* in_sizes, int n_in,
                              void* d_out, int out_size, void* d_ws, size_t ws_size,
                              hipStream_t stream) {
  (void)in_sizes; (void)n_in; (void)out_size; (void)ws_size;
  const int*   x      = (const int*)  d_in[0];
  const float* t      = (const float*)d_in[1];
  const float* s      = (const float*)d_in[2];
  // d_in[3], d_in[4] (y_t, y_s) unused by reference
  const float* h0     = (const float*)d_in[5];
  const int*   au     = (const int*)  d_in[6];
  const float* enc_W  = (const float*)d_in[7];
  const float* user_W = (const float*)d_in[8];
  const float* W_ih   = (const float*)d_in[9];
  const float* W_hh   = (const float*)d_in[10];
  const float* b_ih   = (const float*)d_in[11];
  const float* b_hh   = (const float*)d_in[12];
  const float* fc_W   = (const float*)d_in[13];
  const float* fc_b   = (const float*)d_in[14];

  float* y = (float*)d_out;
  float* hlast = y + Y_ELEMS;

  char* ws = (char*)d_ws;
  short* giV   = (short*)(ws + 0);          // 10000x768 bf16 (biases folded)
  short* A2    = (short*)(ws + 15360000);   // 16384x512 bf16
  short* fcWb  = (short*)(ws + 32137216);   // 10000x512 bf16
  short* encWb = (short*)(ws + 42377216);   // 10000x256 bf16
  short* WihB  = (short*)(ws + 47497216);   // 768x256 bf16
  float* gout  = (float*)(ws + 47890432);   // 256x64x256 f32 GRU hiddens

  fpp_prep<<<1024, 256, 0, stream>>>(enc_W, W_ih, fc_W, user_W, au,
                                     encWb, WihB, fcWb, A2);
  // giV = enc_W @ W_ih.T + b_ih (+ b_hh for n<512); bf16 out
  fpp_gemm_bt<true><<<79 * 6, 256, 0, stream>>>(encWb, WihB, giV, b_ih, b_hh, 512,
                                                10000, 768, 256, 768, 79, 6, 1);
  fpp_gru<<<4, 512, 0, stream>>>(x, h0, W_hh, b_hh, giV, gout, hlast);
  fpp_attn<<<dim3(64, 4), 256, 0, stream>>>(t, s, gout, A2);
  // y = A2 @ fc_W.T + fc_b ; f32 out
  fpp_gemm_bt<false><<<128 * 79, 256, 0, stream>>>(A2, fcWb, y, fc_b, nullptr, 0,
                                                   16384, 10000, 512, 10000, 128, 79, 8);
}

// Round 2
// 1344.271 us; speedup vs baseline: 1.0062x; 1.0062x over previous
//
#include <hip/hip_runtime.h>
#include <stdint.h>

// FlashbackPlusPlus: embed->GRU->spatiotemporal causal attention->FC
// S=256 U=64 H=256 V=10000
#define S_LEN 256
#define U_LEN 64
#define H_DIM 256
#define V_DIM 10000
#define Y_ELEMS 163840000LL  // S*U*V

typedef short bf16x8 __attribute__((ext_vector_type(8)));
typedef float f32x4 __attribute__((ext_vector_type(4)));

__device__ __forceinline__ short f2bf(float f) {
  union { float f; uint32_t u; } v; v.f = f;
  uint32_t r = v.u + 0x7FFFu + ((v.u >> 16) & 1u);  // RNE
  return (short)(r >> 16);
}
__device__ __forceinline__ float bf2f(short s) {
  union { uint32_t u; float f; } v; v.u = ((uint32_t)(uint16_t)s) << 16;
  return v.f;
}

// global -> LDS async copy, 16B per lane. LDS dest = wave-uniform base + lane*16.
__device__ __forceinline__ void gload_lds16(const void* g, void* l) {
  __builtin_amdgcn_global_load_lds(
      (const __attribute__((address_space(1))) char*)(uintptr_t)g,
      (__attribute__((address_space(3))) char*)(uintptr_t)l, 16, 0, 0);
}

// ---------------------------------------------------------------------------
// prep: f32->bf16 weight conversions + A2 user-embedding half
// ---------------------------------------------------------------------------
__global__ __launch_bounds__(256) void fpp_prep(
    const float* __restrict__ enc_W, const float* __restrict__ W_ih,
    const float* __restrict__ fc_W, const float* __restrict__ user_W,
    const int* __restrict__ active_user,
    short* __restrict__ encWb, short* __restrict__ WihB,
    short* __restrict__ fcWb, short* __restrict__ A2) {
  const int tid = blockIdx.x * 256 + threadIdx.x;
  const int stride = gridDim.x * 256;
  for (int i = tid; i < V_DIM * H_DIM; i += stride) encWb[i] = f2bf(enc_W[i]);
  for (int i = tid; i < 3 * H_DIM * H_DIM; i += stride) WihB[i] = f2bf(W_ih[i]);
  for (int i = tid; i < V_DIM * 2 * H_DIM; i += stride) fcWb[i] = f2bf(fc_W[i]);
  // A2 rows r = s*64+u ; cols [256,512) = user_W[active_user[u]]
  for (int i = tid; i < 16384 * 256; i += stride) {
    const int row = i >> 8, k = i & 255;
    const int au = active_user[row & 63];
    A2[(int64_t)row * 512 + 256 + k] = f2bf(user_W[(int64_t)au * 256 + k]);
  }
}

// ---------------------------------------------------------------------------
// GEMM (B^T form): C[m,n] = sum_k A[m,k]*B[n,k] (+bias1[n] (+bias2[n] if n<lim))
// bf16 inputs, f32 accum; 128x128 tile, BK=64, 4 waves, double-buffered LDS,
// global_load_lds staging (m97 structure).
// OMODE: 0 = f32 linear, 1 = bf16 linear, 2 = bf16 gi-packed [m][c][4]
// ---------------------------------------------------------------------------
template <int OMODE>
__global__ __launch_bounds__(256) void fpp_gemm_bt(
    const short* __restrict__ A, const short* __restrict__ B, void* __restrict__ C,
    const float* __restrict__ bias1, const float* __restrict__ bias2, int bias2_limit,
    int M, int N, int K, int ldc, int MT, int NT, int SUPER) {
  // m-supertile mapping: SUPER consecutive m-tiles share the whole B panel in L2
  const int bid = blockIdx.x;
  const int per_super = SUPER * NT;
  const int srow = bid / per_super;
  const int rrem = bid - srow * per_super;
  const int mi = srow * SUPER + (rrem % SUPER);
  const int ni = rrem / SUPER;
  const int m0 = mi * 128, n0 = ni * 128;

  __shared__ __attribute__((aligned(16))) short As[2][128 * 64];
  __shared__ __attribute__((aligned(16))) short Bs[2][128 * 64];

  const int tid = threadIdx.x;
  const int lane = tid & 63;
  const int wv = tid >> 6;
  const int wr = wv >> 1, wc = wv & 1;

  f32x4 acc[4][4];
#pragma unroll
  for (int a_ = 0; a_ < 4; ++a_)
#pragma unroll
    for (int b_ = 0; b_ < 4; ++b_) acc[a_][b_] = f32x4{0.f, 0.f, 0.f, 0.f};

  auto stage = [&](int buf, int k0) {
#pragma unroll
    for (int c = 0; c < 4; ++c) {
      const int chunk = c * 256 + tid;        // 16B chunk id
      const int row = chunk >> 3, kc8 = chunk & 7;
      int gr = m0 + row; gr = (gr < M) ? gr : (M - 1);
      gload_lds16(A + (int64_t)gr * K + k0 + kc8 * 8,
                  (char*)&As[buf][0] + (c * 256 + wv * 64) * 16);
    }
#pragma unroll
    for (int c = 0; c < 4; ++c) {
      const int chunk = c * 256 + tid;
      const int row = chunk >> 3, kc8 = chunk & 7;
      int gn = n0 + row; gn = (gn < N) ? gn : (N - 1);
      gload_lds16(B + (int64_t)gn * K + k0 + kc8 * 8,
                  (char*)&Bs[buf][0] + (c * 256 + wv * 64) * 16);
    }
  };

  const int nk = K >> 6;
  stage(0, 0);
  asm volatile("s_waitcnt vmcnt(0)" ::: "memory");
  __syncthreads();
  for (int ks = 0; ks < nk; ++ks) {
    const int cur = ks & 1;
    if (ks + 1 < nk) stage(cur ^ 1, (ks + 1) << 6);  // async prefetch next K-tile
#pragma unroll
    for (int kk = 0; kk < 2; ++kk) {
      bf16x8 af[4], bfr[4];
#pragma unroll
      for (int mt = 0; mt < 4; ++mt)
        af[mt] = *(const bf16x8*)&As[cur][(wr * 64 + mt * 16 + (lane & 15)) * 64 +
                                          kk * 32 + (lane >> 4) * 8];
#pragma unroll
      for (int nt = 0; nt < 4; ++nt)
        bfr[nt] = *(const bf16x8*)&Bs[cur][(wc * 64 + nt * 16 + (lane & 15)) * 64 +
                                           kk * 32 + (lane >> 4) * 8];
#pragma unroll
      for (int mt = 0; mt < 4; ++mt)
#pragma unroll
        for (int nt = 0; nt < 4; ++nt)
          acc[mt][nt] = __builtin_amdgcn_mfma_f32_16x16x32_bf16(
              af[mt], bfr[nt], acc[mt][nt], 0, 0, 0);
    }
    asm volatile("s_waitcnt vmcnt(0)" ::: "memory");
    __syncthreads();
  }

  // epilogue: D layout row=(lane>>4)*4+r (M dim), col=lane&15 (N dim)
#pragma unroll
  for (int nt = 0; nt < 4; ++nt) {
    const int col = n0 + wc * 64 + nt * 16 + (lane & 15);
    if (col >= N) continue;
    float badd = 0.f;
    if (bias1) badd += bias1[col];
    if (bias2 && col < bias2_limit) badd += bias2[col];
#pragma unroll
    for (int mt = 0; mt < 4; ++mt) {
      const int rbase = m0 + wr * 64 + mt * 16 + (lane >> 4) * 4;
#pragma unroll
      for (int r = 0; r < 4; ++r) {
        const int row = rbase + r;
        if (row < M) {
          const float v = acc[mt][nt][r] + badd;
          if (OMODE == 0)
            ((float*)C)[(int64_t)row * ldc + col] = v;
          else if (OMODE == 1)
            ((short*)C)[(int64_t)row * ldc + col] = f2bf(v);
          else  // gi-packed: [row][col&255][gate], gate = col>>8, stride 4
            ((short*)C)[(int64_t)row * 1024 + ((col & 255) << 2) + (col >> 8)] = f2bf(v);
        }
      }
    }
  }
}

// ---------------------------------------------------------------------------
// GRU: 4 blocks x 16 users x 8 waves, 2 waves/SIMD (VGPR cap 256).
// W_hh bf16 fragments resident in VGPRs (48 frags = 192 VGPR/wave). Wave w
// owns gate-triples for c in [32w,32w+32) -> gates are acc-register-local.
// gi rows (packed [c][4] = r,z,n,pad) staged async to LDS via global_load_lds;
// gate phase reads 1 ds_read_b64 per cell. 2 barriers/step.
// ---------------------------------------------------------------------------
__global__ __launch_bounds__(512, 2) void fpp_gru(
    const int* __restrict__ x, const float* __restrict__ h0,
    const float* __restrict__ W_hh, const float* __restrict__ b_hh,
    const short* __restrict__ giV, float* __restrict__ out,
    float* __restrict__ hlast) {
  __shared__ __attribute__((aligned(16))) short h_lds[16 * 264];    // [u][c] pad 8
  __shared__ __attribute__((aligned(16))) short gi_lds[16 * 1024];  // [u][c][4]
  __shared__ __attribute__((aligned(16))) int x_lds[256 * 16];

  const int tid = threadIdx.x;
  const int lane = tid & 63;
  const int wv = tid >> 6;  // wave 0..7
  const int u0 = blockIdx.x * 16;
  const int g = lane >> 4;
  const int lo = lane & 15;

  for (int i = tid; i < 256 * 16; i += 512)
    x_lds[i] = x[(i >> 4) * 64 + u0 + (i & 15)];

  // preload W_hh B-fragments: B_op[k][n] = W_hh[n][k]; lane: n=n0t+lo, k=kc*32+g*8+j
  bf16x8 Wf[6][8];
  {
    const int n0t[6] = {32 * wv,       32 * wv + 16,       256 + 32 * wv,
                        256 + 32 * wv + 16, 512 + 32 * wv, 512 + 32 * wv + 16};
#pragma unroll
    for (int tt = 0; tt < 6; ++tt) {
      const float* wrow = W_hh + (int64_t)(n0t[tt] + lo) * 256 + g * 8;
#pragma unroll
      for (int kc = 0; kc < 8; ++kc) {
        const float* p = wrow + kc * 32;
        bf16x8 f;
#pragma unroll
        for (int j = 0; j < 8; ++j) f[j] = f2bf(p[j]);
        Wf[tt][kc] = f;
      }
    }
  }
  // b_hh for n-gate (r/z parts folded into giV); b_hh[n], n = 512 + 32w + 16tp + lo
  const float bhh0 = b_hh[512 + 32 * wv + lo];
  const float bhh1 = b_hh[512 + 32 * wv + 16 + lo];

  // h cells owned by this lane: u = g*4+r, c = 32w + tp*16 + lo
  float hreg[2][4];
#pragma unroll
  for (int tp = 0; tp < 2; ++tp)
#pragma unroll
    for (int r = 0; r < 4; ++r) {
      const int u = g * 4 + r, c = 32 * wv + tp * 16 + lo;
      const float v = h0[(u0 + u) * 256 + c];
      hreg[tp][r] = v;
      h_lds[u * 264 + c] = f2bf(v);
    }
  __syncthreads();

  for (int s = 0; s < 256; ++s) {
    // async-stage packed gi rows for users 2w, 2w+1 (4 calls x 1KB, linear)
    {
      const int xid0 = x_lds[s * 16 + 2 * wv];
      const int xid1 = x_lds[s * 16 + 2 * wv + 1];
#pragma unroll
      for (int c = 0; c < 4; ++c) {
        const int p = c * 64 + lane;     // chunk 0..255 over the 2-row region
        const int xid = (p >= 128) ? xid1 : xid0;
        const int pin = p & 127;         // 16B chunk within row
        gload_lds16(giV + (int64_t)xid * 1024 + pin * 8,
                    (char*)gi_lds + wv * 4096 + c * 1024);
      }
    }

    // gh = h @ W_hh^T : 48 MFMAs, acc[4],acc[5] init with b_hh (n-gate)
    f32x4 acc[6];
#pragma unroll
    for (int tt = 0; tt < 4; ++tt) acc[tt] = f32x4{0.f, 0.f, 0.f, 0.f};
    acc[4] = f32x4{bhh0, bhh0, bhh0, bhh0};
    acc[5] = f32x4{bhh1, bhh1, bhh1, bhh1};
#pragma unroll
    for (int kc = 0; kc < 8; ++kc) {
      const bf16x8 a = *(const bf16x8*)&h_lds[lo * 264 + kc * 32 + g * 8];
#pragma unroll
      for (int tt = 0; tt < 6; ++tt)
        acc[tt] = __builtin_amdgcn_mfma_f32_16x16x32_bf16(a, Wf[tt][kc], acc[tt], 0, 0, 0);
    }
    asm volatile("s_waitcnt vmcnt(0)" ::: "memory");  // gi landed (covered by MFMA phase)
    __syncthreads();                                  // barrier1: gi visible, h reads done

    // gates: fully register-local (acc tiles align with cell ownership)
#pragma unroll
    for (int tp = 0; tp < 2; ++tp) {
#pragma unroll
      for (int r = 0; r < 4; ++r) {
        const int u = g * 4 + r;
        const int c = 32 * wv + tp * 16 + lo;
        const short4 gv = *(const short4*)((const char*)gi_lds + u * 2048 + c * 8);
        const float gir = bf2f(gv.x);
        const float giz = bf2f(gv.y);
        const float gin = bf2f(gv.z);
        const float xr = acc[0 + tp][r] + gir;
        const float rr = __builtin_amdgcn_rcpf(1.f + __builtin_amdgcn_exp2f(-1.4426950408889634f * xr));
        const float xz = acc[2 + tp][r] + giz;
        const float zz = __builtin_amdgcn_rcpf(1.f + __builtin_amdgcn_exp2f(-1.4426950408889634f * xz));
        float xn = gin + rr * acc[4 + tp][r];
        xn = fminf(fmaxf(xn, -12.f), 12.f);
        const float E = __builtin_amdgcn_exp2f(2.8853900817779268f * xn);
        const float nn = (E - 1.f) * __builtin_amdgcn_rcpf(E + 1.f);
        const float hv = nn + zz * (hreg[tp][r] - nn);
        hreg[tp][r] = hv;
        h_lds[u * 264 + c] = f2bf(hv);
        out[((int64_t)s * 64 + u0 + u) * 256 + c] = hv;
      }
    }
    __syncthreads();  // barrier2: h writes visible before next MFMA phase
  }

#pragma unroll
  for (int tp = 0; tp < 2; ++tp)
#pragma unroll
    for (int r = 0; r < 4; ++r) {
      const int u = g * 4 + r, c = 32 * wv + tp * 16 + lo;
      hlast[(u0 + u) * 256 + c] = hreg[tp][r];
    }
}

// ---------------------------------------------------------------------------
// attention: per (u, i-block of 64): loop causal j-blocks; w in LDS; weighted
// sum of GRU hiddens; writes bf16 into A2[:, 0:256]. f32 vector math.
// ---------------------------------------------------------------------------
__global__ __launch_bounds__(256) void fpp_attn(
    const float* __restrict__ t_g, const float* __restrict__ s_g,
    const float* __restrict__ gout, short* __restrict__ A2) {
  const int u = blockIdx.x;   // 0..63
  const int ib = blockIdx.y;  // 0..3
  const int tid = threadIdx.x;
  const int iloc = tid >> 2;  // 0..63
  const int q = tid & 3;      // h quarter (64 each)

  __shared__ __attribute__((aligned(16))) float out_lds[64][272];  // q-seg stride 68
  __shared__ __attribute__((aligned(16))) float w_lds[64][65];
  __shared__ float ti[64], si0[64], si1[64], tj[64], sj0[64], sj1[64], sum_lds[64];

  if (tid < 64) {
    const int ig = ib * 64 + tid;
    ti[tid] = t_g[ig * 64 + u];
    si0[tid] = s_g[(ig * 64 + u) * 2 + 0];
    si1[tid] = s_g[(ig * 64 + u) * 2 + 1];
    sum_lds[tid] = 0.f;
  }

  f32x4 accv[16];
#pragma unroll
  for (int hh = 0; hh < 16; ++hh) accv[hh] = f32x4{0.f, 0.f, 0.f, 0.f};

  const int igl = ib * 64 + iloc;

  for (int jb = 0; jb <= ib; ++jb) {
    __syncthreads();  // protect LDS vs previous iteration readers
    {
      const int jj = tid >> 2;
      const float* src = gout + ((int64_t)(jb * 64 + jj) * 64 + u) * 256 + q * 64;
#pragma unroll
      for (int hh = 0; hh < 16; ++hh)
        *(f32x4*)&out_lds[jj][q * 68 + hh * 4] = *(const f32x4*)(src + hh * 4);
    }
    if (tid < 64) {
      const int jg = jb * 64 + tid;
      tj[tid] = t_g[jg * 64 + u];
      sj0[tid] = s_g[(jg * 64 + u) * 2 + 0];
      sj1[tid] = s_g[(jg * 64 + u) * 2 + 1];
    }
    __syncthreads();
    {
      const float tiv = ti[iloc], p0 = si0[iloc], p1 = si1[iloc];
#pragma unroll
      for (int jj = 0; jj < 16; ++jj) {
        const int j = q * 16 + jj;
        const int jgl = jb * 64 + j;
        const float dt = tiv - tj[j];
        // f_t = (cos(2*pi*dt)+1)*0.5*exp(-0.1*dt); v_cos takes revolutions
        const float ft = (__builtin_amdgcn_cosf(dt) + 1.f) * 0.5f *
                         __builtin_amdgcn_exp2f(-0.14426950408889634f * dt);
        const float dx = p0 - sj0[j], dy = p1 - sj1[j];
        const float ds = __builtin_amdgcn_sqrtf(dx * dx + dy * dy);
        const float fs = __builtin_amdgcn_exp2f(-144.26950408889634f * ds);
        float wvv = ft * fs + 1e-10f;
        if (jgl > igl) wvv = 0.f;  // causal
        w_lds[iloc][j] = wvv;
      }
    }
    __syncthreads();
    if (tid < 64) {
      float sm = 0.f;
#pragma unroll
      for (int j = 0; j < 64; ++j) sm += w_lds[tid][j];
      sum_lds[tid] += sm;
    }
    for (int j = 0; j < 64; ++j) {
      const float wvv = w_lds[iloc][j];
#pragma unroll
      for (int hh = 0; hh < 16; ++hh) {
        const f32x4 o = *(const f32x4*)&out_lds[j][q * 68 + hh * 4];
        accv[hh] += o * wvv;
      }
    }
  }
  __syncthreads();
  const float inv = 1.f / sum_lds[iloc];
  short* dst = A2 + (int64_t)((ib * 64 + iloc) * 64 + u) * 512 + q * 64;
#pragma unroll
  for (int hh = 0; hh < 16; ++hh) {
    const f32x4 v = accv[hh] * inv;
    short4 sv;
    sv.x = f2bf(v[0]); sv.y = f2bf(v[1]); sv.z = f2bf(v[2]); sv.w = f2bf(v[3]);
    *(short4*)(dst + hh * 4) = sv;
  }
}

// ---------------------------------------------------------------------------
extern "C" void kernel_launch(void* const* d_in, const int* in_sizes, int n_in,
                              void* d_out, int out_size, void* d_ws, size_t ws_size,
                              hipStream_t stream) {
  (void)in_sizes; (void)n_in; (void)out_size; (void)ws_size;
  const int*   x      = (const int*)  d_in[0];
  const float* t      = (const float*)d_in[1];
  const float* s      = (const float*)d_in[2];
  // d_in[3], d_in[4] (y_t, y_s) unused by reference
  const float* h0     = (const float*)d_in[5];
  const int*   au     = (const int*)  d_in[6];
  const float* enc_W  = (const float*)d_in[7];
  const float* user_W = (const float*)d_in[8];
  const float* W_ih   = (const float*)d_in[9];
  const float* W_hh   = (const float*)d_in[10];
  const float* b_ih   = (const float*)d_in[11];
  const float* b_hh   = (const float*)d_in[12];
  const float* fc_W   = (const float*)d_in[13];
  const float* fc_b   = (const float*)d_in[14];

  float* y = (float*)d_out;
  float* hlast = y + Y_ELEMS;

  char* ws = (char*)d_ws;
  short* giV   = (short*)(ws + 0);          // 10000x256x4 bf16, packed [c][r,z,n,pad]
  short* A2    = (short*)(ws + 20480000);   // 16384x512 bf16
  short* fcWb  = (short*)(ws + 37257216);   // 10000x512 bf16
  short* encWb = (short*)(ws + 47497216);   // 10000x256 bf16
  short* WihB  = (short*)(ws + 52617216);   // 768x256 bf16
  float* gout  = (float*)(ws + 53010432);   // 256x64x256 f32 GRU hiddens

  fpp_prep<<<1024, 256, 0, stream>>>(enc_W, W_ih, fc_W, user_W, au,
                                     encWb, WihB, fcWb, A2);
  // giV = enc_W @ W_ih.T + b_ih (+ b_hh for n<512); bf16, gi-packed layout
  fpp_gemm_bt<2><<<79 * 6, 256, 0, stream>>>(encWb, WihB, giV, b_ih, b_hh, 512,
                                             10000, 768, 256, 0, 79, 6, 1);
  fpp_gru<<<4, 512, 0, stream>>>(x, h0, W_hh, b_hh, giV, gout, hlast);
  fpp_attn<<<dim3(64, 4), 256, 0, stream>>>(t, s, gout, A2);
  // y = A2 @ fc_W.T + fc_b ; f32 out
  fpp_gemm_bt<0><<<128 * 79, 256, 0, stream>>>(A2, fcWb, y, fc_b, nullptr, 0,
                                               16384, 10000, 512, 10000, 128, 79, 8);
}

// Round 3
// 1192.042 us; speedup vs baseline: 1.1347x; 1.1277x over previous
//
#include <hip/hip_runtime.h>
#include <stdint.h>

// FlashbackPlusPlus: embed->GRU->spatiotemporal causal attention->FC
// S=256 U=64 H=256 V=10000
#define S_LEN 256
#define U_LEN 64
#define H_DIM 256
#define V_DIM 10000
#define Y_ELEMS 163840000LL  // S*U*V

typedef short bf16x8 __attribute__((ext_vector_type(8)));
typedef float f32x4 __attribute__((ext_vector_type(4)));

__device__ __forceinline__ short f2bf(float f) {
  union { float f; uint32_t u; } v; v.f = f;
  uint32_t r = v.u + 0x7FFFu + ((v.u >> 16) & 1u);  // RNE
  return (short)(r >> 16);
}
__device__ __forceinline__ float bf2f(short s) {
  union { uint32_t u; float f; } v; v.u = ((uint32_t)(uint16_t)s) << 16;
  return v.f;
}

// global -> LDS async copy, 16B per lane. LDS dest = wave-uniform base + lane*16.
__device__ __forceinline__ void gload_lds16(const void* g, void* l) {
  __builtin_amdgcn_global_load_lds(
      (const __attribute__((address_space(1))) char*)(uintptr_t)g,
      (__attribute__((address_space(3))) char*)(uintptr_t)l, 16, 0, 0);
}

// ---------------------------------------------------------------------------
// prep: f32->bf16 weight conversions + A2 user-embedding half + W_hh fragment
// pack (fragment-linear so the GRU preamble is 48 coalesced dwordx4 loads).
// ---------------------------------------------------------------------------
__global__ __launch_bounds__(256) void fpp_prep(
    const float* __restrict__ enc_W, const float* __restrict__ W_ih,
    const float* __restrict__ fc_W, const float* __restrict__ user_W,
    const float* __restrict__ W_hh, const int* __restrict__ active_user,
    short* __restrict__ encWb, short* __restrict__ WihB,
    short* __restrict__ fcWb, short* __restrict__ A2,
    short* __restrict__ WhhFrag) {
  const int tid = blockIdx.x * 256 + threadIdx.x;
  const int stride = gridDim.x * 256;
  for (int i = tid; i < V_DIM * H_DIM; i += stride) encWb[i] = f2bf(enc_W[i]);
  for (int i = tid; i < 3 * H_DIM * H_DIM; i += stride) WihB[i] = f2bf(W_ih[i]);
  for (int i = tid; i < V_DIM * 2 * H_DIM; i += stride) fcWb[i] = f2bf(fc_W[i]);
  // A2 rows r = s*64+u ; cols [256,512) = user_W[active_user[u]]
  for (int i = tid; i < 16384 * 256; i += stride) {
    const int row = i >> 8, k = i & 255;
    const int au = active_user[row & 63];
    A2[(int64_t)row * 512 + 256 + k] = f2bf(user_W[(int64_t)au * 256 + k]);
  }
  // WhhFrag[i], i = (((wv*6+tt)*8+kc)*64+lane)*8+j ; holds W_hh[n][k] bf16 with
  // n = (tt>>1)*256 + 32*wv + (tt&1)*16 + (lane&15), k = kc*32 + (lane>>4)*8 + j
  for (int i = tid; i < 768 * 256; i += stride) {
    const int j = i & 7, ln = (i >> 3) & 63, kc = (i >> 9) & 7, t12 = i >> 12;
    const int tt = t12 % 6, wvv = t12 / 6;
    const int n = (tt >> 1) * 256 + 32 * wvv + (tt & 1) * 16 + (ln & 15);
    const int k = kc * 32 + (ln >> 4) * 8 + j;
    WhhFrag[i] = f2bf(W_hh[n * 256 + k]);
  }
}

// ---------------------------------------------------------------------------
// GEMM (B^T form): C[m,n] = sum_k A[m,k]*B[n,k] (+bias1[n] (+bias2[n] if n<lim))
// bf16 inputs, f32 accum; 128x128 tile, BK=64, 4 waves, double-buffered LDS,
// global_load_lds staging (m97 structure).
// OMODE: 0 = f32 linear, 1 = bf16 linear, 2 = bf16 gi-packed [m][c][4]
// ---------------------------------------------------------------------------
template <int OMODE>
__global__ __launch_bounds__(256) void fpp_gemm_bt(
    const short* __restrict__ A, const short* __restrict__ B, void* __restrict__ C,
    const float* __restrict__ bias1, const float* __restrict__ bias2, int bias2_limit,
    int M, int N, int K, int ldc, int MT, int NT, int SUPER) {
  // m-supertile mapping: SUPER consecutive m-tiles share the whole B panel in L2
  const int bid = blockIdx.x;
  const int per_super = SUPER * NT;
  const int srow = bid / per_super;
  const int rrem = bid - srow * per_super;
  const int mi = srow * SUPER + (rrem % SUPER);
  const int ni = rrem / SUPER;
  const int m0 = mi * 128, n0 = ni * 128;

  __shared__ __attribute__((aligned(16))) short As[2][128 * 64];
  __shared__ __attribute__((aligned(16))) short Bs[2][128 * 64];

  const int tid = threadIdx.x;
  const int lane = tid & 63;
  const int wv = tid >> 6;
  const int wr = wv >> 1, wc = wv & 1;

  f32x4 acc[4][4];
#pragma unroll
  for (int a_ = 0; a_ < 4; ++a_)
#pragma unroll
    for (int b_ = 0; b_ < 4; ++b_) acc[a_][b_] = f32x4{0.f, 0.f, 0.f, 0.f};

  auto stage = [&](int buf, int k0) {
#pragma unroll
    for (int c = 0; c < 4; ++c) {
      const int chunk = c * 256 + tid;        // 16B chunk id
      const int row = chunk >> 3, kc8 = chunk & 7;
      int gr = m0 + row; gr = (gr < M) ? gr : (M - 1);
      gload_lds16(A + (int64_t)gr * K + k0 + kc8 * 8,
                  (char*)&As[buf][0] + (c * 256 + wv * 64) * 16);
    }
#pragma unroll
    for (int c = 0; c < 4; ++c) {
      const int chunk = c * 256 + tid;
      const int row = chunk >> 3, kc8 = chunk & 7;
      int gn = n0 + row; gn = (gn < N) ? gn : (N - 1);
      gload_lds16(B + (int64_t)gn * K + k0 + kc8 * 8,
                  (char*)&Bs[buf][0] + (c * 256 + wv * 64) * 16);
    }
  };

  const int nk = K >> 6;
  stage(0, 0);
  asm volatile("s_waitcnt vmcnt(0)" ::: "memory");
  __syncthreads();
  for (int ks = 0; ks < nk; ++ks) {
    const int cur = ks & 1;
    if (ks + 1 < nk) stage(cur ^ 1, (ks + 1) << 6);  // async prefetch next K-tile
#pragma unroll
    for (int kk = 0; kk < 2; ++kk) {
      bf16x8 af[4], bfr[4];
#pragma unroll
      for (int mt = 0; mt < 4; ++mt)
        af[mt] = *(const bf16x8*)&As[cur][(wr * 64 + mt * 16 + (lane & 15)) * 64 +
                                          kk * 32 + (lane >> 4) * 8];
#pragma unroll
      for (int nt = 0; nt < 4; ++nt)
        bfr[nt] = *(const bf16x8*)&Bs[cur][(wc * 64 + nt * 16 + (lane & 15)) * 64 +
                                           kk * 32 + (lane >> 4) * 8];
#pragma unroll
      for (int mt = 0; mt < 4; ++mt)
#pragma unroll
        for (int nt = 0; nt < 4; ++nt)
          acc[mt][nt] = __builtin_amdgcn_mfma_f32_16x16x32_bf16(
              af[mt], bfr[nt], acc[mt][nt], 0, 0, 0);
    }
    asm volatile("s_waitcnt vmcnt(0)" ::: "memory");
    __syncthreads();
  }

  // epilogue: D layout row=(lane>>4)*4+r (M dim), col=lane&15 (N dim)
#pragma unroll
  for (int nt = 0; nt < 4; ++nt) {
    const int col = n0 + wc * 64 + nt * 16 + (lane & 15);
    if (col >= N) continue;
    float badd = 0.f;
    if (bias1) badd += bias1[col];
    if (bias2 && col < bias2_limit) badd += bias2[col];
#pragma unroll
    for (int mt = 0; mt < 4; ++mt) {
      const int rbase = m0 + wr * 64 + mt * 16 + (lane >> 4) * 4;
#pragma unroll
      for (int r = 0; r < 4; ++r) {
        const int row = rbase + r;
        if (row < M) {
          const float v = acc[mt][nt][r] + badd;
          if (OMODE == 0)
            ((float*)C)[(int64_t)row * ldc + col] = v;
          else if (OMODE == 1)
            ((short*)C)[(int64_t)row * ldc + col] = f2bf(v);
          else  // gi-packed: [row][col&255][gate], gate = col>>8, stride 4
            ((short*)C)[(int64_t)row * 1024 + ((col & 255) << 2) + (col >> 8)] = f2bf(v);
        }
      }
    }
  }
}

// ---------------------------------------------------------------------------
// GRU: 4 blocks x 16 users x 8 waves, exactly 2 waves/SIMD (waves_per_eu(2,2)
// + 82KB LDS force a 256-VGPR budget so the 48 W_hh fragments stay resident).
// Wave w owns gate-triples for c in [32w,32w+32) -> gates acc-register-local.
// gi rows (packed [c][4] = r,z,n,pad) double-buffered in LDS: loads for step
// s+1 issued at top of step s, waited after the gate phase (full-step hiding).
// ---------------------------------------------------------------------------
__global__ __attribute__((amdgpu_waves_per_eu(2, 2))) __launch_bounds__(512)
void fpp_gru(
    const int* __restrict__ x, const float* __restrict__ h0,
    const short* __restrict__ WhhFrag, const float* __restrict__ b_hh,
    const short* __restrict__ giV, float* __restrict__ out,
    float* __restrict__ hlast) {
  __shared__ __attribute__((aligned(16))) short h_lds[16 * 264];        // 8448 B
  __shared__ __attribute__((aligned(16))) short gi_lds[2][16 * 1024];   // 65536 B
  __shared__ __attribute__((aligned(16))) uint16_t x_lds[256 * 16];     // 8192 B

  const int tid = threadIdx.x;
  const int lane = tid & 63;
  const int wv = tid >> 6;  // wave 0..7
  const int u0 = blockIdx.x * 16;
  const int g = lane >> 4;
  const int lo = lane & 15;

  for (int i = tid; i < 256 * 16; i += 512)
    x_lds[i] = (uint16_t)x[(i >> 4) * 64 + u0 + (i & 15)];

  // preload W_hh B-fragments: 48 coalesced dwordx4 loads from fragment-linear pack
  bf16x8 Wf[6][8];
  {
    const bf16x8* wfp = (const bf16x8*)WhhFrag;
#pragma unroll
    for (int tt = 0; tt < 6; ++tt)
#pragma unroll
      for (int kc = 0; kc < 8; ++kc)
        Wf[tt][kc] = wfp[((wv * 6 + tt) * 8 + kc) * 64 + lane];
  }
  // b_hh for n-gate (r/z parts folded into giV)
  const float bhh0 = b_hh[512 + 32 * wv + lo];
  const float bhh1 = b_hh[512 + 32 * wv + 16 + lo];

  // h cells owned by this lane: u = g*4+r, c = 32w + tp*16 + lo
  float hreg[2][4];
#pragma unroll
  for (int tp = 0; tp < 2; ++tp)
#pragma unroll
    for (int r = 0; r < 4; ++r) {
      const int u = g * 4 + r, c = 32 * wv + tp * 16 + lo;
      const float v = h0[(u0 + u) * 256 + c];
      hreg[tp][r] = v;
      h_lds[u * 264 + c] = f2bf(v);
    }
  __syncthreads();  // x_lds + h_lds visible

  // stage gi rows (packed, 2KB/user) for step ss into buffer buf
  auto stage_gi = [&](int buf, int ss) {
    const int xid0 = x_lds[ss * 16 + 2 * wv];
    const int xid1 = x_lds[ss * 16 + 2 * wv + 1];
#pragma unroll
    for (int c = 0; c < 4; ++c) {
      const int p = c * 64 + lane;     // chunk 0..255 over the 2-row region
      const int xid = (p >= 128) ? xid1 : xid0;
      const int pin = p & 127;         // 16B chunk within row
      gload_lds16(giV + (int64_t)xid * 1024 + pin * 8,
                  (char*)gi_lds[buf] + wv * 4096 + c * 1024);
    }
  };

  stage_gi(0, 0);
  asm volatile("s_waitcnt vmcnt(0)" ::: "memory");
  __syncthreads();  // gi buf0 valid

  for (int s = 0; s < 256; ++s) {
    if (s < 255) stage_gi((s + 1) & 1, s + 1);  // async prefetch next step's gi

    // gh = h @ W_hh^T : 48 MFMAs, acc[4],acc[5] init with b_hh (n-gate)
    f32x4 acc[6];
#pragma unroll
    for (int tt = 0; tt < 4; ++tt) acc[tt] = f32x4{0.f, 0.f, 0.f, 0.f};
    acc[4] = f32x4{bhh0, bhh0, bhh0, bhh0};
    acc[5] = f32x4{bhh1, bhh1, bhh1, bhh1};
#pragma unroll
    for (int kc = 0; kc < 8; ++kc) {
      const bf16x8 a = *(const bf16x8*)&h_lds[lo * 264 + kc * 32 + g * 8];
#pragma unroll
      for (int tt = 0; tt < 6; ++tt)
        acc[tt] = __builtin_amdgcn_mfma_f32_16x16x32_bf16(a, Wf[tt][kc], acc[tt], 0, 0, 0);
    }
    __syncthreads();  // barrier1: h_lds reads done; gi[s&1] valid from prev iter

    // gates: fully register-local (acc tiles align with cell ownership)
    const char* gbase = (const char*)gi_lds[s & 1];
#pragma unroll
    for (int tp = 0; tp < 2; ++tp) {
#pragma unroll
      for (int r = 0; r < 4; ++r) {
        const int u = g * 4 + r;
        const int c = 32 * wv + tp * 16 + lo;
        const short4 gv = *(const short4*)(gbase + u * 2048 + c * 8);
        const float gir = bf2f(gv.x);
        const float giz = bf2f(gv.y);
        const float gin = bf2f(gv.z);
        const float xr = acc[0 + tp][r] + gir;
        const float rr = __builtin_amdgcn_rcpf(1.f + __builtin_amdgcn_exp2f(-1.4426950408889634f * xr));
        const float xz = acc[2 + tp][r] + giz;
        const float zz = __builtin_amdgcn_rcpf(1.f + __builtin_amdgcn_exp2f(-1.4426950408889634f * xz));
        float xn = gin + rr * acc[4 + tp][r];
        xn = fminf(fmaxf(xn, -12.f), 12.f);
        const float E = __builtin_amdgcn_exp2f(2.8853900817779268f * xn);
        const float nn = (E - 1.f) * __builtin_amdgcn_rcpf(E + 1.f);
        const float hv = nn + zz * (hreg[tp][r] - nn);
        hreg[tp][r] = hv;
        h_lds[u * 264 + c] = f2bf(hv);
        out[((int64_t)s * 64 + u0 + u) * 256 + c] = hv;
      }
    }
    asm volatile("s_waitcnt vmcnt(0)" ::: "memory");  // gi(s+1) landed (hidden)
    __syncthreads();  // barrier2: new h + gi(s+1) visible
  }

#pragma unroll
  for (int tp = 0; tp < 2; ++tp)
#pragma unroll
    for (int r = 0; r < 4; ++r) {
      const int u = g * 4 + r, c = 32 * wv + tp * 16 + lo;
      hlast[(u0 + u) * 256 + c] = hreg[tp][r];
    }
}

// ---------------------------------------------------------------------------
// attention: per (u, i-block of 64): loop causal j-blocks; w in LDS; weighted
// sum of GRU hiddens; writes bf16 into A2[:, 0:256]. f32 vector math.
// ---------------------------------------------------------------------------
__global__ __launch_bounds__(256) void fpp_attn(
    const float* __restrict__ t_g, const float* __restrict__ s_g,
    const float* __restrict__ gout, short* __restrict__ A2) {
  const int u = blockIdx.x;   // 0..63
  const int ib = blockIdx.y;  // 0..3
  const int tid = threadIdx.x;
  const int iloc = tid >> 2;  // 0..63
  const int q = tid & 3;      // h quarter (64 each)

  __shared__ __attribute__((aligned(16))) float out_lds[64][272];  // q-seg stride 68
  __shared__ __attribute__((aligned(16))) float w_lds[64][65];
  __shared__ float ti[64], si0[64], si1[64], tj[64], sj0[64], sj1[64], sum_lds[64];

  if (tid < 64) {
    const int ig = ib * 64 + tid;
    ti[tid] = t_g[ig * 64 + u];
    si0[tid] = s_g[(ig * 64 + u) * 2 + 0];
    si1[tid] = s_g[(ig * 64 + u) * 2 + 1];
    sum_lds[tid] = 0.f;
  }

  f32x4 accv[16];
#pragma unroll
  for (int hh = 0; hh < 16; ++hh) accv[hh] = f32x4{0.f, 0.f, 0.f, 0.f};

  const int igl = ib * 64 + iloc;

  for (int jb = 0; jb <= ib; ++jb) {
    __syncthreads();  // protect LDS vs previous iteration readers
    {
      const int jj = tid >> 2;
      const float* src = gout + ((int64_t)(jb * 64 + jj) * 64 + u) * 256 + q * 64;
#pragma unroll
      for (int hh = 0; hh < 16; ++hh)
        *(f32x4*)&out_lds[jj][q * 68 + hh * 4] = *(const f32x4*)(src + hh * 4);
    }
    if (tid < 64) {
      const int jg = jb * 64 + tid;
      tj[tid] = t_g[jg * 64 + u];
      sj0[tid] = s_g[(jg * 64 + u) * 2 + 0];
      sj1[tid] = s_g[(jg * 64 + u) * 2 + 1];
    }
    __syncthreads();
    {
      const float tiv = ti[iloc], p0 = si0[iloc], p1 = si1[iloc];
#pragma unroll
      for (int jj = 0; jj < 16; ++jj) {
        const int j = q * 16 + jj;
        const int jgl = jb * 64 + j;
        const float dt = tiv - tj[j];
        // f_t = (cos(2*pi*dt)+1)*0.5*exp(-0.1*dt); v_cos takes revolutions
        const float ft = (__builtin_amdgcn_cosf(dt) + 1.f) * 0.5f *
                         __builtin_amdgcn_exp2f(-0.14426950408889634f * dt);
        const float dx = p0 - sj0[j], dy = p1 - sj1[j];
        const float ds = __builtin_amdgcn_sqrtf(dx * dx + dy * dy);
        const float fs = __builtin_amdgcn_exp2f(-144.26950408889634f * ds);
        float wvv = ft * fs + 1e-10f;
        if (jgl > igl) wvv = 0.f;  // causal
        w_lds[iloc][j] = wvv;
      }
    }
    __syncthreads();
    if (tid < 64) {
      float sm = 0.f;
#pragma unroll
      for (int j = 0; j < 64; ++j) sm += w_lds[tid][j];
      sum_lds[tid] += sm;
    }
    for (int j = 0; j < 64; ++j) {
      const float wvv = w_lds[iloc][j];
#pragma unroll
      for (int hh = 0; hh < 16; ++hh) {
        const f32x4 o = *(const f32x4*)&out_lds[j][q * 68 + hh * 4];
        accv[hh] += o * wvv;
      }
    }
  }
  __syncthreads();
  const float inv = 1.f / sum_lds[iloc];
  short* dst = A2 + (int64_t)((ib * 64 + iloc) * 64 + u) * 512 + q * 64;
#pragma unroll
  for (int hh = 0; hh < 16; ++hh) {
    const f32x4 v = accv[hh] * inv;
    short4 sv;
    sv.x = f2bf(v[0]); sv.y = f2bf(v[1]); sv.z = f2bf(v[2]); sv.w = f2bf(v[3]);
    *(short4*)(dst + hh * 4) = sv;
  }
}

// ---------------------------------------------------------------------------
extern "C" void kernel_launch(void* const* d_in, const int* in_sizes, int n_in,
                              void* d_out, int out_size, void* d_ws, size_t ws_size,
                              hipStream_t stream) {
  (void)in_sizes; (void)n_in; (void)out_size; (void)ws_size;
  const int*   x      = (const int*)  d_in[0];
  const float* t      = (const float*)d_in[1];
  const float* s      = (const float*)d_in[2];
  // d_in[3], d_in[4] (y_t, y_s) unused by reference
  const float* h0     = (const float*)d_in[5];
  const int*   au     = (const int*)  d_in[6];
  const float* enc_W  = (const float*)d_in[7];
  const float* user_W = (const float*)d_in[8];
  const float* W_ih   = (const float*)d_in[9];
  const float* W_hh   = (const float*)d_in[10];
  const float* b_ih   = (const float*)d_in[11];
  const float* b_hh   = (const float*)d_in[12];
  const float* fc_W   = (const float*)d_in[13];
  const float* fc_b   = (const float*)d_in[14];

  float* y = (float*)d_out;
  float* hlast = y + Y_ELEMS;

  char* ws = (char*)d_ws;
  short* giV   = (short*)(ws + 0);          // 10000x256x4 bf16, packed [c][r,z,n,pad]
  short* A2    = (short*)(ws + 20480000);   // 16384x512 bf16
  short* fcWb  = (short*)(ws + 37257216);   // 10000x512 bf16
  short* encWb = (short*)(ws + 47497216);   // 10000x256 bf16
  short* WihB  = (short*)(ws + 52617216);   // 768x256 bf16
  float* gout  = (float*)(ws + 53010432);   // 256x64x256 f32 GRU hiddens
  // WhhFrag scratch lives inside d_out's y region (written by prep, read by
  // GRU, overwritten by the final GEMM) to avoid growing ws usage.
  short* WhhFrag = (short*)(y + 80000000);  // 768x256 bf16, fragment-linear

  fpp_prep<<<1024, 256, 0, stream>>>(enc_W, W_ih, fc_W, user_W, W_hh, au,
                                     encWb, WihB, fcWb, A2, WhhFrag);
  // giV = enc_W @ W_ih.T + b_ih (+ b_hh for n<512); bf16, gi-packed layout
  fpp_gemm_bt<2><<<79 * 6, 256, 0, stream>>>(encWb, WihB, giV, b_ih, b_hh, 512,
                                             10000, 768, 256, 0, 79, 6, 1);
  fpp_gru<<<4, 512, 0, stream>>>(x, h0, WhhFrag, b_hh, giV, gout, hlast);
  fpp_attn<<<dim3(64, 4), 256, 0, stream>>>(t, s, gout, A2);
  // y = A2 @ fc_W.T + fc_b ; f32 out
  fpp_gemm_bt<0><<<128 * 79, 256, 0, stream>>>(A2, fcWb, y, fc_b, nullptr, 0,
                                               16384, 10000, 512, 10000, 128, 79, 8);
}